// Round 5
// baseline (362.424 us; speedup 1.0000x reference)
//
#include <hip/hip_runtime.h>
#include <math.h>

#define B 32
#define T 2048
#define H 512

#define BM 128
#define BN 128

typedef __attribute__((ext_vector_type(8))) __bf16 bf16x8;
typedef __attribute__((ext_vector_type(4))) __bf16 bf16x4v;
typedef __attribute__((ext_vector_type(4))) float f32x4;
typedef __attribute__((ext_vector_type(8))) float f32x8;
typedef __attribute__((ext_vector_type(4))) float floatx4;

union pack8  { bf16x4v h; uint2 u; };
union fragU  { bf16x4v q[2]; bf16x8 v; };

static __device__ __forceinline__ float fast_tanh(float x) {
    float ex = __expf(2.f * x);
    return 1.f - 2.f * __builtin_amdgcn_rcpf(ex + 1.f);
}

static __device__ __forceinline__ void gl_lds16(const void* g, void* l) {
    __builtin_amdgcn_global_load_lds(
        (const __attribute__((address_space(1))) void*)g,
        (__attribute__((address_space(3))) void*)l, 16, 0, 0);
}

// ---------------- K1: q-projection GEMV + bias; zero ctx; convert v_w -> bf16
// grid (B, 9): s<8 -> GEMV slice; s==8 -> convert v_w chunk b (8192 elements)
__global__ __launch_bounds__(256) void k1_init(const float* __restrict__ query,
                                               const float* __restrict__ q_w,
                                               const float* __restrict__ bias,
                                               const float* __restrict__ v_w,
                                               float* __restrict__ qpb,
                                               unsigned short* __restrict__ wbf,
                                               float* __restrict__ ctx_out) {
    const int b = blockIdx.x;
    const int s = blockIdx.y;           // 0..8
    const int tid = threadIdx.x;

    if (s == 8) {
        // convert v_w slice: elements [b*8192, (b+1)*8192)
        const size_t base = (size_t)b * 8192 + tid * 4;
#pragma unroll
        for (int i = 0; i < 8; ++i) {
            const size_t off = base + (size_t)i * 1024;
            f32x4 a = *(const f32x4*)(v_w + off);
            pack8 p;
            p.h = __builtin_convertvector(a, bf16x4v);
            *(uint2*)(wbf + off) = p.u;
        }
        return;
    }

    const int wave = tid >> 6;
    const int lane = tid & 63;

    if (s < 2) ctx_out[b * H + s * 256 + tid] = 0.f;

    const float* qb = query + (size_t)b * H + lane * 8;
    float4 q0 = *(const float4*)qb;
    float4 q1 = *(const float4*)(qb + 4);

    const int o0 = s * 64 + wave * 16;
#pragma unroll
    for (int i = 0; i < 16; ++i) {
        const int o = o0 + i;
        const float* wr = q_w + (size_t)o * H + lane * 8;
        float4 w0 = *(const float4*)wr;
        float4 w1 = *(const float4*)(wr + 4);
        float acc = w0.x * q0.x + w0.y * q0.y + w0.z * q0.z + w0.w * q0.w +
                    w1.x * q1.x + w1.y * q1.y + w1.z * q1.z + w1.w * q1.w;
#pragma unroll
        for (int m = 1; m < 64; m <<= 1) acc += __shfl_xor(acc, m);
        if (lane == 0) qpb[b * H + o] = acc + bias[o];
    }
}

// ---------------- K2: MFMA GEMM, A = fp32 value converted in-register,
//                  B = bf16 weights via global_load_lds. No atomics: 8 partial slots.
__global__ __launch_bounds__(256) void k2_fused(const float* __restrict__ value,
                                                const unsigned short* __restrict__ wbf,
                                                const float* __restrict__ la,
                                                const float* __restrict__ conv_w,
                                                const float* __restrict__ conv_b,
                                                const float* __restrict__ s_w,
                                                const float* __restrict__ qpb,
                                                float* __restrict__ pre8) {
    __shared__ __align__(16) unsigned short Bs[BN * 32];   // 8 KB
    __shared__ float qpbs[BN], sws[BN], cbs[BN], cw0s[BN], cw1s[BN], cw2s[BN];
    __shared__ float las[BM + 2];

    const int t0 = blockIdx.x * BM;
    const int o0 = blockIdx.y * BN;
    const int b  = blockIdx.z;
    const int tid = threadIdx.x;
    const int wave = tid >> 6;
    const int lane = tid & 63;
    const int tx   = lane & 15;
    const int quad = lane >> 4;
    const int wm = (wave >> 1) * 64;
    const int wn = (wave & 1) * 64;

    if (tid < BN) {
        const int o = o0 + tid;
        qpbs[tid] = qpb[b * H + o];
        sws[tid]  = s_w[o];
        cbs[tid]  = conv_b[o];
        cw0s[tid] = conv_w[o * 3 + 0];
        cw1s[tid] = conv_w[o * 3 + 1];
        cw2s[tid] = conv_w[o * 3 + 2];
    }
    if (tid < BM + 2) {
        const int t = t0 + tid - 1;
        las[tid] = (t >= 0 && t < T) ? la[b * T + t] : 0.f;
    }

    floatx4 acc[4][4];
#pragma unroll
    for (int i = 0; i < 4; ++i)
#pragma unroll
        for (int j = 0; j < 4; ++j) acc[i][j] = (floatx4){0.f, 0.f, 0.f, 0.f};

    // B staging (proven round-4 pattern): wave stages chunks {wave, wave+4}
    const int rB = lane >> 2;
    const int ck = (lane & 3) * 8;
    const unsigned short* gB0 = wbf + (size_t)(o0 + wave * 16 + rB) * H + ck;
    const unsigned short* gB1 = gB0 + (size_t)64 * H;
    unsigned short* lB0 = &Bs[wave * 512];
    unsigned short* lB1 = &Bs[(wave + 4) * 512];

    // A direct per-lane pointer: rows t0+wm+mi*16+tx, cols kc+quad*8
    const float* aptr = value + ((size_t)(b * T + t0 + wm + tx)) * H + quad * 8;

    for (int kc = 0; kc < H; kc += 32) {
        __syncthreads();               // prior Bs frag reads complete
        gl_lds16(gB0, lB0);
        gl_lds16(gB1, lB1);
        gB0 += 32; gB1 += 32;

        // A fragments: load fp32, convert in-register (overlaps B staging drain)
        bf16x8 af[4];
#pragma unroll
        for (int mi = 0; mi < 4; ++mi) {
            const float* p = aptr + (size_t)mi * 16 * H + kc;
            f32x4 lo = *(const f32x4*)p;
            f32x4 hi = *(const f32x4*)(p + 4);
            fragU u;
            u.q[0] = __builtin_convertvector(lo, bf16x4v);
            u.q[1] = __builtin_convertvector(hi, bf16x4v);
            af[mi] = u.v;
        }

        __syncthreads();               // Bs visible

        bf16x8 bfr[4];
#pragma unroll
        for (int ni = 0; ni < 4; ++ni)
            bfr[ni] = *(const bf16x8*)&Bs[(wn + ni * 16 + tx) * 32 + quad * 8];
#pragma unroll
        for (int mi = 0; mi < 4; ++mi)
#pragma unroll
            for (int ni = 0; ni < 4; ++ni)
                acc[mi][ni] = __builtin_amdgcn_mfma_f32_16x16x32_bf16(
                    af[mi], bfr[ni], acc[mi][ni], 0, 0, 0);
    }

    // epilogue: e = tanh(v + qpb + conv); partial score = sum over this 64-o strip
    float sacc[16];
#pragma unroll
    for (int i = 0; i < 16; ++i) sacc[i] = 0.f;

#pragma unroll
    for (int ni = 0; ni < 4; ++ni) {
        const int ol = wn + ni * 16 + tx;
        const float c0 = cw0s[ol], c1 = cw1s[ol], c2 = cw2s[ol];
        const float cb = cbs[ol], qp = qpbs[ol], sw = sws[ol];
#pragma unroll
        for (int mi = 0; mi < 4; ++mi)
#pragma unroll
            for (int r = 0; r < 4; ++r) {
                const int tl = wm + mi * 16 + quad * 4 + r;
                const float conv = c0 * las[tl] + c1 * las[tl + 1] + c2 * las[tl + 2] + cb;
                const float x = acc[mi][ni][r] + qp + conv;
                sacc[mi * 4 + r] += sw * fast_tanh(x);
            }
    }
    // slot = o-tile*2 + wn-half: unique writer per (slot, t) -> plain store
    float* slot = pre8 + ((size_t)(blockIdx.y * 2 + (wn >> 6))) * (B * T) + b * T + t0;
#pragma unroll
    for (int i = 0; i < 16; ++i) {
        float v = sacc[i];
        v += __shfl_xor(v, 1);
        v += __shfl_xor(v, 2);
        v += __shfl_xor(v, 4);
        v += __shfl_xor(v, 8);
        if (tx == 0) {
            const int tl = wm + (i >> 2) * 16 + quad * 4 + (i & 3);
            slot[tl] = v;
        }
    }
}

// ---------------- K3 fused: sum slots + sigmoid + normalize + attn + context
__global__ __launch_bounds__(256) void k3_fused(const float* __restrict__ value,
                                                const float* __restrict__ pre8,
                                                const float* __restrict__ s_b,
                                                float* __restrict__ attn_out,
                                                float* __restrict__ ctx) {
    __shared__ float sm[T];          // 8 KB
    __shared__ float red[4];
    __shared__ float redc[4][H];     // 8 KB
    const int b = blockIdx.x;
    const int slice = blockIdx.y;    // 0..15, each 128 t
    const int tid = threadIdx.x;
    const float sb = s_b[0];

    float s[8];
    float loc = 0.f;
#pragma unroll
    for (int i = 0; i < 8; ++i) {
        const int t = tid + i * 256;
        float p = sb;
#pragma unroll
        for (int sl = 0; sl < 8; ++sl)
            p += pre8[(size_t)sl * (B * T) + b * T + t];
        const float sg = 1.f / (1.f + expf(-p));
        s[i] = sg;
        sm[t] = sg;
        loc += sg;
    }
#pragma unroll
    for (int m = 1; m < 64; m <<= 1) loc += __shfl_xor(loc, m);
    if ((tid & 63) == 0) red[tid >> 6] = loc;
    __syncthreads();
    const float inv = 1.f / (red[0] + red[1] + red[2] + red[3]);
    if (slice == 0) {
#pragma unroll
        for (int i = 0; i < 8; ++i) attn_out[b * T + tid + i * 256] = s[i] * inv;
    }

    // context slice: cols (tid&63)*8, t-phase tid>>6
    const int col = (tid & 63) * 8;
    const int tp  = tid >> 6;
    f32x8 a;
#pragma unroll
    for (int i = 0; i < 8; ++i) a[i] = 0.f;
    const float* vb = value + (size_t)b * T * H + col;
    const int tbeg = slice * 128;
    for (int t = tbeg + tp; t < tbeg + 128; t += 4) {
        const float w = sm[t] * inv;
        f32x4 v0 = *(const f32x4*)(vb + (size_t)t * H);
        f32x4 v1 = *(const f32x4*)(vb + (size_t)t * H + 4);
#pragma unroll
        for (int i = 0; i < 4; ++i) { a[i] += w * v0[i]; a[i + 4] += w * v1[i]; }
    }
    *(f32x4*)&redc[tp][col]     = (f32x4){a[0], a[1], a[2], a[3]};
    *(f32x4*)&redc[tp][col + 4] = (f32x4){a[4], a[5], a[6], a[7]};
    __syncthreads();
    if (tid < 128) {
        const int h = tid * 4;
        f32x4 r0 = *(const f32x4*)&redc[0][h];
        f32x4 r1 = *(const f32x4*)&redc[1][h];
        f32x4 r2 = *(const f32x4*)&redc[2][h];
        f32x4 r3 = *(const f32x4*)&redc[3][h];
        atomicAdd(&ctx[b * H + h + 0], r0[0] + r1[0] + r2[0] + r3[0]);
        atomicAdd(&ctx[b * H + h + 1], r0[1] + r1[1] + r2[1] + r3[1]);
        atomicAdd(&ctx[b * H + h + 2], r0[2] + r1[2] + r2[2] + r3[2]);
        atomicAdd(&ctx[b * H + h + 3], r0[3] + r1[3] + r2[3] + r3[3]);
    }
}

extern "C" void kernel_launch(void* const* d_in, const int* in_sizes, int n_in,
                              void* d_out, int out_size, void* d_ws, size_t ws_size,
                              hipStream_t stream) {
    const float* query  = (const float*)d_in[0];
    const float* value  = (const float*)d_in[1];
    const float* la     = (const float*)d_in[2];
    const float* conv_w = (const float*)d_in[3];
    const float* conv_b = (const float*)d_in[4];
    const float* q_w    = (const float*)d_in[5];
    const float* v_w    = (const float*)d_in[6];
    const float* s_w    = (const float*)d_in[7];
    const float* s_b    = (const float*)d_in[8];
    const float* bias   = (const float*)d_in[9];

    float* out  = (float*)d_out;
    float* ctx  = out;            // (B, H)
    float* attn = out + B * H;    // (B, T)

    float* qpb  = (float*)d_ws;                       // B*H floats
    float* pre8 = qpb + B * H;                        // 8*B*T floats
    unsigned short* wbf = (unsigned short*)(pre8 + 8 * B * T);   // H*H bf16

    dim3 g1(B, 9);
    k1_init<<<g1, 256, 0, stream>>>(query, q_w, bias, v_w, qpb, wbf, ctx);

    dim3 g2(T / BM, H / BN, B);
    k2_fused<<<g2, 256, 0, stream>>>(value, wbf, la, conv_w, conv_b, s_w, qpb, pre8);

    dim3 g3(B, 16);
    k3_fused<<<g3, 256, 0, stream>>>(value, pre8, s_b, attn, ctx);
}

// Round 6
// 305.962 us; speedup vs baseline: 1.1845x; 1.1845x over previous
//
#include <hip/hip_runtime.h>
#include <math.h>

#define B 32
#define T 2048
#define H 512

#define BMT 128            // t rows per k2 block
#define APAD 40            // padded row stride (bf16) for LDS tiles

typedef __attribute__((ext_vector_type(8))) __bf16 bf16x8;
typedef __attribute__((ext_vector_type(4))) __bf16 bf16x4v;
typedef __attribute__((ext_vector_type(4))) float f32x4;
typedef __attribute__((ext_vector_type(8))) float f32x8;
typedef __attribute__((ext_vector_type(4))) float floatx4;

union pack8 { bf16x4v h; uint2 u; };

static __device__ __forceinline__ float fast_tanh(float x) {
    float ex = __expf(2.f * x);
    return 1.f - 2.f * __builtin_amdgcn_rcpf(ex + 1.f);
}

// ---------------- K1: q-projection GEMV + bias; zero ctx; convert v_w -> bf16
// grid (B, 9): s<8 -> GEMV slice; s==8 -> convert v_w chunk b (8192 elements)
__global__ __launch_bounds__(256) void k1_init(const float* __restrict__ query,
                                               const float* __restrict__ q_w,
                                               const float* __restrict__ bias,
                                               const float* __restrict__ v_w,
                                               float* __restrict__ qpb,
                                               unsigned short* __restrict__ wbf,
                                               float* __restrict__ ctx_out) {
    const int b = blockIdx.x;
    const int s = blockIdx.y;           // 0..8
    const int tid = threadIdx.x;

    if (s == 8) {
        const size_t base = (size_t)b * 8192 + tid * 4;
#pragma unroll
        for (int i = 0; i < 8; ++i) {
            const size_t off = base + (size_t)i * 1024;
            f32x4 a = *(const f32x4*)(v_w + off);
            pack8 p;
            p.h = __builtin_convertvector(a, bf16x4v);
            *(uint2*)(wbf + off) = p.u;
        }
        return;
    }

    const int wave = tid >> 6;
    const int lane = tid & 63;

    if (s < 2) ctx_out[b * H + s * 256 + tid] = 0.f;

    const float* qb = query + (size_t)b * H + lane * 8;
    float4 q0 = *(const float4*)qb;
    float4 q1 = *(const float4*)(qb + 4);

    const int o0 = s * 64 + wave * 16;
#pragma unroll
    for (int i = 0; i < 16; ++i) {
        const int o = o0 + i;
        const float* wr = q_w + (size_t)o * H + lane * 8;
        float4 w0 = *(const float4*)wr;
        float4 w1 = *(const float4*)(wr + 4);
        float acc = w0.x * q0.x + w0.y * q0.y + w0.z * q0.z + w0.w * q0.w +
                    w1.x * q1.x + w1.y * q1.y + w1.z * q1.z + w1.w * q1.w;
#pragma unroll
        for (int m = 1; m < 64; m <<= 1) acc += __shfl_xor(acc, m);
        if (lane == 0) qpb[b * H + o] = acc + bias[o];
    }
}

// ---------------- K2: one block = 128 t x ALL 512 o. value read once, coalesced.
// 1024 threads = 16 waves arranged 2 (t) x 8 (o), each wave a 64x64 MFMA patch.
__global__ __launch_bounds__(1024, 4) void k2_big(const float* __restrict__ value,
                                                  const unsigned short* __restrict__ wbf,
                                                  const float* __restrict__ la,
                                                  const float* __restrict__ conv_w,
                                                  const float* __restrict__ conv_b,
                                                  const float* __restrict__ s_w,
                                                  const float* __restrict__ qpb,
                                                  float* __restrict__ pre) {
    __shared__ __align__(16) unsigned short As[BMT * APAD];  // 10 KB
    __shared__ __align__(16) unsigned short Bs[H * APAD];    // 40 KB
    __shared__ float qpbs[H], sws[H], cbs[H], cw0s[H], cw1s[H], cw2s[H];  // 12 KB
    __shared__ float las[BMT + 2];
    __shared__ float redp[BMT][8];                            // 4 KB

    const int t0 = blockIdx.x * BMT;
    const int b  = blockIdx.y;
    const int tid = threadIdx.x;
    const int wave = tid >> 6;
    const int lane = tid & 63;
    const int tx   = lane & 15;
    const int quad = lane >> 4;
    const int wm   = (wave & 1) * 64;    // t offset within tile
    const int wn   = (wave >> 1) * 64;   // o offset (global, 0..448)

    if (tid < H) {
        qpbs[tid] = qpb[b * H + tid];
        sws[tid]  = s_w[tid];
        cbs[tid]  = conv_b[tid];
        cw0s[tid] = conv_w[tid * 3 + 0];
        cw1s[tid] = conv_w[tid * 3 + 1];
        cw2s[tid] = conv_w[tid * 3 + 2];
    }
    if (tid < BMT + 2) {
        const int t = t0 + tid - 1;
        las[tid] = (t >= 0 && t < T) ? la[b * T + t] : 0.f;
    }

    floatx4 acc[4][4];
#pragma unroll
    for (int i = 0; i < 4; ++i)
#pragma unroll
        for (int j = 0; j < 4; ++j) acc[i][j] = (floatx4){0.f, 0.f, 0.f, 0.f};

    // A staging: thread -> row tid>>3 (0..127), float-cols (tid&7)*4
    const int arow = tid >> 3;
    const int acol = (tid & 7) * 4;
    const float* agp = value + ((size_t)b * T + t0 + arow) * H + acol;
    // B staging: thread -> row tid>>1 (0..511), bf16-cols (tid&1)*16
    const int brow = tid >> 1;
    const int bcol = (tid & 1) * 16;
    const unsigned short* bgp = wbf + (size_t)brow * H + bcol;

    for (int kc = 0; kc < H; kc += 32) {
        f32x4 av = *(const f32x4*)(agp + kc);
        uint4 bv0 = *(const uint4*)(bgp + kc);
        uint4 bv1 = *(const uint4*)(bgp + kc + 8);

        __syncthreads();     // previous iteration's fragment reads complete

        pack8 p;
        p.h = __builtin_convertvector(av, bf16x4v);
        *(uint2*)&As[arow * APAD + acol] = p.u;
        *(uint4*)&Bs[brow * APAD + bcol] = bv0;
        *(uint4*)&Bs[brow * APAD + bcol + 8] = bv1;

        __syncthreads();     // tiles visible

        bf16x8 af[4], bfr[4];
#pragma unroll
        for (int mi = 0; mi < 4; ++mi)
            af[mi] = *(const bf16x8*)&As[(wm + mi * 16 + tx) * APAD + quad * 8];
#pragma unroll
        for (int ni = 0; ni < 4; ++ni)
            bfr[ni] = *(const bf16x8*)&Bs[(wn + ni * 16 + tx) * APAD + quad * 8];
#pragma unroll
        for (int mi = 0; mi < 4; ++mi)
#pragma unroll
            for (int ni = 0; ni < 4; ++ni)
                acc[mi][ni] = __builtin_amdgcn_mfma_f32_16x16x32_bf16(
                    af[mi], bfr[ni], acc[mi][ni], 0, 0, 0);
    }

    // epilogue: e = tanh(v + qpb + conv); wave-partial score over its 64 o
    float sacc[16];
#pragma unroll
    for (int i = 0; i < 16; ++i) sacc[i] = 0.f;

#pragma unroll
    for (int ni = 0; ni < 4; ++ni) {
        const int ol = wn + ni * 16 + tx;
        const float c0 = cw0s[ol], c1 = cw1s[ol], c2 = cw2s[ol];
        const float cb = cbs[ol], qp = qpbs[ol], sw = sws[ol];
#pragma unroll
        for (int mi = 0; mi < 4; ++mi)
#pragma unroll
            for (int r = 0; r < 4; ++r) {
                const int tl = wm + mi * 16 + quad * 4 + r;
                const float conv = c0 * las[tl] + c1 * las[tl + 1] + c2 * las[tl + 2] + cb;
                const float x = acc[mi][ni][r] + qp + conv;
                sacc[mi * 4 + r] += sw * fast_tanh(x);
            }
    }
    __syncthreads();         // As/Bs reads done; reuse LDS region conceptually (redp separate)
#pragma unroll
    for (int i = 0; i < 16; ++i) {
        float v = sacc[i];
        v += __shfl_xor(v, 1);
        v += __shfl_xor(v, 2);
        v += __shfl_xor(v, 4);
        v += __shfl_xor(v, 8);
        if (tx == 0) {
            const int tl = wm + (i >> 2) * 16 + quad * 4 + (i & 3);
            redp[tl][wave >> 1] = v;
        }
    }
    __syncthreads();
    if (tid < BMT) {
        float p = 0.f;
#pragma unroll
        for (int w = 0; w < 8; ++w) p += redp[tid][w];
        pre[b * T + t0 + tid] = p;
    }
}

// ---------------- K3 fused: sigmoid + normalize + attn write + context
__global__ __launch_bounds__(256) void k3_fused(const float* __restrict__ value,
                                                const float* __restrict__ pre,
                                                const float* __restrict__ s_b,
                                                float* __restrict__ attn_out,
                                                float* __restrict__ ctx) {
    __shared__ float sm[T];          // 8 KB
    __shared__ float red[4];
    __shared__ float redc[4][H];     // 8 KB
    const int b = blockIdx.x;
    const int slice = blockIdx.y;    // 0..15, each 128 t
    const int tid = threadIdx.x;
    const float sb = s_b[0];

    float s[8];
    float loc = 0.f;
#pragma unroll
    for (int i = 0; i < 8; ++i) {
        const int t = tid + i * 256;
        const float p = pre[b * T + t] + sb;
        const float sg = 1.f / (1.f + expf(-p));
        s[i] = sg;
        sm[t] = sg;
        loc += sg;
    }
#pragma unroll
    for (int m = 1; m < 64; m <<= 1) loc += __shfl_xor(loc, m);
    if ((tid & 63) == 0) red[tid >> 6] = loc;
    __syncthreads();
    const float inv = 1.f / (red[0] + red[1] + red[2] + red[3]);
    if (slice == 0) {
#pragma unroll
        for (int i = 0; i < 8; ++i) attn_out[b * T + tid + i * 256] = s[i] * inv;
    }

    const int col = (tid & 63) * 8;
    const int tp  = tid >> 6;
    f32x8 a;
#pragma unroll
    for (int i = 0; i < 8; ++i) a[i] = 0.f;
    const float* vb = value + (size_t)b * T * H + col;
    const int tbeg = slice * 128;
    for (int t = tbeg + tp; t < tbeg + 128; t += 4) {
        const float w = sm[t] * inv;
        f32x4 v0 = *(const f32x4*)(vb + (size_t)t * H);
        f32x4 v1 = *(const f32x4*)(vb + (size_t)t * H + 4);
#pragma unroll
        for (int i = 0; i < 4; ++i) { a[i] += w * v0[i]; a[i + 4] += w * v1[i]; }
    }
    *(f32x4*)&redc[tp][col]     = (f32x4){a[0], a[1], a[2], a[3]};
    *(f32x4*)&redc[tp][col + 4] = (f32x4){a[4], a[5], a[6], a[7]};
    __syncthreads();
    if (tid < 128) {
        const int h = tid * 4;
        f32x4 r0 = *(const f32x4*)&redc[0][h];
        f32x4 r1 = *(const f32x4*)&redc[1][h];
        f32x4 r2 = *(const f32x4*)&redc[2][h];
        f32x4 r3 = *(const f32x4*)&redc[3][h];
        atomicAdd(&ctx[b * H + h + 0], r0[0] + r1[0] + r2[0] + r3[0]);
        atomicAdd(&ctx[b * H + h + 1], r0[1] + r1[1] + r2[1] + r3[1]);
        atomicAdd(&ctx[b * H + h + 2], r0[2] + r1[2] + r2[2] + r3[2]);
        atomicAdd(&ctx[b * H + h + 3], r0[3] + r1[3] + r2[3] + r3[3]);
    }
}

extern "C" void kernel_launch(void* const* d_in, const int* in_sizes, int n_in,
                              void* d_out, int out_size, void* d_ws, size_t ws_size,
                              hipStream_t stream) {
    const float* query  = (const float*)d_in[0];
    const float* value  = (const float*)d_in[1];
    const float* la     = (const float*)d_in[2];
    const float* conv_w = (const float*)d_in[3];
    const float* conv_b = (const float*)d_in[4];
    const float* q_w    = (const float*)d_in[5];
    const float* v_w    = (const float*)d_in[6];
    const float* s_w    = (const float*)d_in[7];
    const float* s_b    = (const float*)d_in[8];
    const float* bias   = (const float*)d_in[9];

    float* out  = (float*)d_out;
    float* ctx  = out;            // (B, H)
    float* attn = out + B * H;    // (B, T)

    float* qpb = (float*)d_ws;                     // B*H floats
    float* pre = qpb + B * H;                      // B*T floats
    unsigned short* wbf = (unsigned short*)(pre + B * T);   // H*H bf16

    dim3 g1(B, 9);
    k1_init<<<g1, 256, 0, stream>>>(query, q_w, bias, v_w, qpb, wbf, ctx);

    dim3 g2(T / BMT, B);
    k2_big<<<g2, 1024, 0, stream>>>(value, wbf, la, conv_w, conv_b, s_w, qpb, pre);

    dim3 g3(B, 16);
    k3_fused<<<g3, 256, 0, stream>>>(value, pre, s_b, attn, ctx);
}

// Round 7
// 280.297 us; speedup vs baseline: 1.2930x; 1.0916x over previous
//
#include <hip/hip_runtime.h>
#include <math.h>

#define B 32
#define T 2048
#define H 512

#define BT2 64             // t rows per k2 block
#define APAD 40            // padded LDS row stride for A (bf16 elems)

typedef __attribute__((ext_vector_type(8))) __bf16 bf16x8;
typedef __attribute__((ext_vector_type(4))) __bf16 bf16x4v;
typedef __attribute__((ext_vector_type(4))) float f32x4;
typedef __attribute__((ext_vector_type(4))) float floatx4;

union pack8 { bf16x4v h; uint2 u; };

static __device__ __forceinline__ void gl_lds16(const void* g, void* l) {
    __builtin_amdgcn_global_load_lds(
        (const __attribute__((address_space(1))) void*)g,
        (__attribute__((address_space(3))) void*)l, 16, 0, 0);
}

// ---------------- K_init: flat grid.
// blocks [0,256): GEMV q-proj (b=blk>>3, s=blk&7)
// blocks [256,288): convert v_w slice -> bf16
// block 288: zero ctx_num (B*H) and denom (B)
__global__ __launch_bounds__(256) void k_init(const float* __restrict__ query,
                                              const float* __restrict__ q_w,
                                              const float* __restrict__ bias,
                                              const float* __restrict__ v_w,
                                              float* __restrict__ qpb,
                                              unsigned short* __restrict__ wbf,
                                              float* __restrict__ ctx_num,
                                              float* __restrict__ denom) {
    const int blk = blockIdx.x;
    const int tid = threadIdx.x;

    if (blk >= 288) {
        // zero accumulators
#pragma unroll
        for (int i = 0; i < 16; ++i) {
            const int off = tid * 4 + i * 1024;
            *(f32x4*)(ctx_num + off) = (f32x4){0.f, 0.f, 0.f, 0.f};
        }
        if (tid < B) denom[tid] = 0.f;
        return;
    }
    if (blk >= 256) {
        const int c = blk - 256;
        const size_t base = (size_t)c * 8192 + tid * 4;
#pragma unroll
        for (int i = 0; i < 8; ++i) {
            const size_t off = base + (size_t)i * 1024;
            f32x4 a = *(const f32x4*)(v_w + off);
            pack8 p;
            p.h = __builtin_convertvector(a, bf16x4v);
            *(uint2*)(wbf + off) = p.u;
        }
        return;
    }

    const int b = blk >> 3;
    const int s = blk & 7;
    const int wave = tid >> 6;
    const int lane = tid & 63;

    const float* qb = query + (size_t)b * H + lane * 8;
    float4 q0 = *(const float4*)qb;
    float4 q1 = *(const float4*)(qb + 4);

    const int o0 = s * 64 + wave * 16;
#pragma unroll
    for (int i = 0; i < 16; ++i) {
        const int o = o0 + i;
        const float* wr = q_w + (size_t)o * H + lane * 8;
        float4 w0 = *(const float4*)wr;
        float4 w1 = *(const float4*)(wr + 4);
        float acc = w0.x * q0.x + w0.y * q0.y + w0.z * q0.z + w0.w * q0.w +
                    w1.x * q1.x + w1.y * q1.y + w1.z * q1.z + w1.w * q1.w;
#pragma unroll
        for (int m = 1; m < 64; m <<= 1) acc += __shfl_xor(acc, m);
        if (lane == 0) qpb[b * H + o] = acc + bias[o];
    }
}

// ---------------- K2: 64t x 512o per block; score + sigmoid + ctx partial, fused.
__global__ __launch_bounds__(512, 4) void k2_fused(const float* __restrict__ value,
                                                   const unsigned short* __restrict__ wbf,
                                                   const float* __restrict__ la,
                                                   const float* __restrict__ conv_w,
                                                   const float* __restrict__ conv_b,
                                                   const float* __restrict__ s_w,
                                                   const float* __restrict__ qpb,
                                                   const float* __restrict__ s_b,
                                                   float* __restrict__ pre_sg,
                                                   float* __restrict__ ctx_num,
                                                   float* __restrict__ denom) {
    __shared__ __align__(16) unsigned short As[BT2 * APAD];   // 5 KB, padded
    __shared__ __align__(16) unsigned short Bs[H * 32];       // 32 KB, glds layout
    __shared__ float las[BT2 + 2];
    __shared__ float redp[BT2][9];                            // padded
    __shared__ float sgs[BT2];

    const int t0 = blockIdx.x * BT2;
    const int b  = blockIdx.y;
    const int tid = threadIdx.x;
    const int wave = tid >> 6;        // 0..7
    const int lane = tid & 63;
    const int tx   = lane & 15;
    const int quad = lane >> 4;
    const int wn   = wave * 64;       // this wave's o-strip

    if (tid < BT2 + 2) {
        const int t = t0 + tid - 1;
        las[tid] = (t >= 0 && t < T) ? la[b * T + t] : 0.f;
    }

    // per-lane epilogue constants (4 o's per lane)
    float qp4[4], sw4[4], cb4[4], c04[4], c14[4], c24[4];
#pragma unroll
    for (int ni = 0; ni < 4; ++ni) {
        const int ol = wn + ni * 16 + tx;
        qp4[ni] = qpb[b * H + ol];
        sw4[ni] = s_w[ol];
        cb4[ni] = conv_b[ol];
        c04[ni] = conv_w[ol * 3 + 0];
        c14[ni] = conv_w[ol * 3 + 1];
        c24[ni] = conv_w[ol * 3 + 2];
    }

    floatx4 acc[4][4];
#pragma unroll
    for (int i = 0; i < 4; ++i)
#pragma unroll
        for (int j = 0; j < 4; ++j) acc[i][j] = (floatx4){0.f, 0.f, 0.f, 0.f};

    // A staging: thread -> row tid>>3 (0..63), float-col (tid&7)*4
    const int arow = tid >> 3;
    const int acol = (tid & 7) * 4;
    const float* agp = value + ((size_t)b * T + t0 + arow) * H + acol;
    // B staging via glds: 32 chunks of 16 rows; wave stages chunks w, w+8, w+16, w+24
    const int brow = lane >> 2;       // row within chunk
    const int bcol = (lane & 3) * 8;
    const unsigned short* gB[4];
    unsigned short* lB[4];
#pragma unroll
    for (int c = 0; c < 4; ++c) {
        const int chunk = wave + c * 8;
        gB[c] = wbf + (size_t)(chunk * 16 + brow) * H + bcol;
        lB[c] = &Bs[chunk * 512];
    }

    for (int kc = 0; kc < H; kc += 32) {
        f32x4 av = *(const f32x4*)(agp + kc);

        __syncthreads();              // prior frag reads complete
#pragma unroll
        for (int c = 0; c < 4; ++c) gl_lds16(gB[c] + kc, lB[c]);

        pack8 p;
        p.h = __builtin_convertvector(av, bf16x4v);
        *(uint2*)&As[arow * APAD + acol] = p.u;

        __syncthreads();              // staging visible (vmcnt+lgkm drained)

        bf16x8 af[4], bfr[4];
#pragma unroll
        for (int mi = 0; mi < 4; ++mi)
            af[mi] = *(const bf16x8*)&As[(mi * 16 + tx) * APAD + quad * 8];
#pragma unroll
        for (int ni = 0; ni < 4; ++ni)
            bfr[ni] = *(const bf16x8*)&Bs[(wn + ni * 16 + tx) * 32 + quad * 8];
#pragma unroll
        for (int mi = 0; mi < 4; ++mi)
#pragma unroll
            for (int ni = 0; ni < 4; ++ni)
                acc[mi][ni] = __builtin_amdgcn_mfma_f32_16x16x32_bf16(
                    af[mi], bfr[ni], acc[mi][ni], 0, 0, 0);
    }

    // epilogue: tanh + s_w reduce over this wave's 64 o
    float sacc[16];
#pragma unroll
    for (int i = 0; i < 16; ++i) sacc[i] = 0.f;
#pragma unroll
    for (int ni = 0; ni < 4; ++ni) {
#pragma unroll
        for (int mi = 0; mi < 4; ++mi)
#pragma unroll
            for (int r = 0; r < 4; ++r) {
                const int tl = mi * 16 + quad * 4 + r;
                const float conv = c04[ni] * las[tl] + c14[ni] * las[tl + 1] +
                                   c24[ni] * las[tl + 2] + cb4[ni];
                const float x = acc[mi][ni][r] + qp4[ni] + conv;
                const float ex = __expf(2.f * x);
                const float th = 1.f - 2.f * __builtin_amdgcn_rcpf(ex + 1.f);
                sacc[mi * 4 + r] += sw4[ni] * th;
            }
    }
#pragma unroll
    for (int i = 0; i < 16; ++i) {
        float v = sacc[i];
        v += __shfl_xor(v, 1);
        v += __shfl_xor(v, 2);
        v += __shfl_xor(v, 4);
        v += __shfl_xor(v, 8);
        if (tx == 0) redp[(i >> 2) * 16 + quad * 4 + (i & 3)][wave] = v;
    }
    __syncthreads();

    // wave 0: score -> sigmoid -> sgs + pre_sg + denom atomic
    if (tid < BT2) {
        float sc = s_b[0];
#pragma unroll
        for (int w = 0; w < 8; ++w) sc += redp[tid][w];
        const float sg = 1.f / (1.f + __expf(-sc));
        sgs[tid] = sg;
        pre_sg[b * T + t0 + tid] = sg;
        float dsum = sg;
#pragma unroll
        for (int m = 1; m < 64; m <<= 1) dsum += __shfl_xor(dsum, m);
        if (tid == 0) atomicAdd(&denom[b], dsum);
    }
    __syncthreads();                  // sgs visible; Bs free for overlay

    // ctx partial: num[h] += sum_t sgs[t]*value[t][h]; Bs overlaid as redc[4][512]
    float* redc = (float*)Bs;
    const int h4 = (tid & 127) * 4;
    const int tp = tid >> 7;          // 0..3
    f32x4 a = {0.f, 0.f, 0.f, 0.f};
    const float* vb = value + ((size_t)b * T + t0) * H + h4;
    for (int t = tp; t < BT2; t += 4) {
        const float w = sgs[t];
        f32x4 v = *(const f32x4*)(vb + (size_t)t * H);
        a.x += w * v.x; a.y += w * v.y; a.z += w * v.z; a.w += w * v.w;
    }
    *(f32x4*)&redc[tp * 512 + h4] = a;
    __syncthreads();
    if (tid < 128) {
        const int h = tid * 4;
        f32x4 r0 = *(const f32x4*)&redc[0 * 512 + h];
        f32x4 r1 = *(const f32x4*)&redc[1 * 512 + h];
        f32x4 r2 = *(const f32x4*)&redc[2 * 512 + h];
        f32x4 r3 = *(const f32x4*)&redc[3 * 512 + h];
        atomicAdd(&ctx_num[b * H + h + 0], r0.x + r1.x + r2.x + r3.x);
        atomicAdd(&ctx_num[b * H + h + 1], r0.y + r1.y + r2.y + r3.y);
        atomicAdd(&ctx_num[b * H + h + 2], r0.z + r1.z + r2.z + r3.z);
        atomicAdd(&ctx_num[b * H + h + 3], r0.w + r1.w + r2.w + r3.w);
    }
}

// ---------------- K3: scale by 1/denom
__global__ __launch_bounds__(256) void k3_scale(const float* __restrict__ pre_sg,
                                                const float* __restrict__ ctx_num,
                                                const float* __restrict__ denom,
                                                float* __restrict__ attn_out,
                                                float* __restrict__ ctx) {
    const int b = blockIdx.x;
    const int tid = threadIdx.x;
    const float inv = 1.f / denom[b];
#pragma unroll
    for (int i = 0; i < 8; ++i) {
        const int t = tid + i * 256;
        attn_out[b * T + t] = pre_sg[b * T + t] * inv;
    }
#pragma unroll
    for (int i = 0; i < 2; ++i) {
        const int h = tid + i * 256;
        ctx[b * H + h] = ctx_num[b * H + h] * inv;
    }
}

extern "C" void kernel_launch(void* const* d_in, const int* in_sizes, int n_in,
                              void* d_out, int out_size, void* d_ws, size_t ws_size,
                              hipStream_t stream) {
    const float* query  = (const float*)d_in[0];
    const float* value  = (const float*)d_in[1];
    const float* la     = (const float*)d_in[2];
    const float* conv_w = (const float*)d_in[3];
    const float* conv_b = (const float*)d_in[4];
    const float* q_w    = (const float*)d_in[5];
    const float* v_w    = (const float*)d_in[6];
    const float* s_w    = (const float*)d_in[7];
    const float* s_b    = (const float*)d_in[8];
    const float* bias   = (const float*)d_in[9];

    float* out  = (float*)d_out;
    float* ctx  = out;            // (B, H)
    float* attn = out + B * H;    // (B, T)

    float* qpb     = (float*)d_ws;                 // B*H
    float* pre_sg  = qpb + B * H;                  // B*T
    float* ctx_num = pre_sg + B * T;               // B*H
    float* denom   = ctx_num + B * H;              // B
    unsigned short* wbf = (unsigned short*)(denom + 64);   // H*H bf16

    k_init<<<289, 256, 0, stream>>>(query, q_w, bias, v_w, qpb, wbf, ctx_num, denom);

    dim3 g2(T / BT2, B);
    k2_fused<<<g2, 512, 0, stream>>>(value, wbf, la, conv_w, conv_b, s_w, qpb, s_b,
                                     pre_sg, ctx_num, denom);

    k3_scale<<<B, 256, 0, stream>>>(pre_sg, ctx_num, denom, attn, ctx);
}